// Round 1
// baseline (345.166 us; speedup 1.0000x reference)
//
#include <hip/hip_runtime.h>

#define L     1001
#define H     256
#define B_DIM 32
#define KSHOT 50

typedef float  f32x4   __attribute__((ext_vector_type(4)));
typedef short  short8  __attribute__((ext_vector_type(8)));
typedef unsigned short ushort8 __attribute__((ext_vector_type(8)));
typedef float  float4a __attribute__((ext_vector_type(4), aligned(4)));

__device__ __forceinline__ unsigned short f2bf(float x) {
  unsigned int u = __float_as_uint(x);
  u += 0x7FFFu + ((u >> 16) & 1u);           // RNE
  return (unsigned short)(u >> 16);
}
__device__ __forceinline__ float bf2f(unsigned short h) {
  return __uint_as_float(((unsigned int)h) << 16);
}

// ---------------------------------------------------------------- qe: q . emb
__global__ __launch_bounds__(256) void qe_kernel(const float* __restrict__ q,
                                                 const float* __restrict__ emb,
                                                 float* __restrict__ qe) {
  int wid  = (blockIdx.x << 2) + (threadIdx.x >> 6);   // one wave per (b,i) row
  int lane = threadIdx.x & 63;
  if (wid >= B_DIM * L) return;
  const float4a qv = *(const float4a*)(q + (size_t)wid * H + lane * 4);
  float acc[6];
#pragma unroll
  for (int c = 0; c < 6; ++c) {
    float4a ev = *(const float4a*)(emb + c * H + lane * 4);
    acc[c] = qv.x * ev.x + qv.y * ev.y + qv.z * ev.z + qv.w * ev.w;
  }
#pragma unroll
  for (int c = 0; c < 6; ++c)
#pragma unroll
    for (int o = 32; o; o >>= 1) acc[c] += __shfl_xor(acc[c], o, 64);
  if (lane == 0) {
    float* dst = qe + (size_t)wid * 6;
    dst[0] = acc[0]; dst[1] = acc[1]; dst[2] = acc[2];
    dst[3] = acc[3]; dst[4] = acc[4]; dst[5] = acc[5];
  }
}

// ------------------------------------------------- v[b][j][h] -> vt[b][h][j] bf16 (j padded to 1024 with 0)
__global__ __launch_bounds__(256) void vt_kernel(const float* __restrict__ v,
                                                 unsigned short* __restrict__ vt) {
  const int b = blockIdx.z, ht = blockIdx.y, jt = blockIdx.x;
  const int j0 = jt * 64, h0 = ht * 64;
  const int t = threadIdx.x;
  __shared__ unsigned short tile[64][68];
#pragma unroll
  for (int it = 0; it < 4; ++it) {
    int j = (t >> 4) + it * 16;
    int h = (t & 15) * 4;
    int gj = j0 + j;
    float4a val = {0.f, 0.f, 0.f, 0.f};
    if (gj < L) val = *(const float4a*)(v + ((size_t)b * L + gj) * H + h0 + h);
    tile[j][h + 0] = f2bf(val.x);
    tile[j][h + 1] = f2bf(val.y);
    tile[j][h + 2] = f2bf(val.z);
    tile[j][h + 3] = f2bf(val.w);
  }
  __syncthreads();
#pragma unroll
  for (int it = 0; it < 2; ++it) {
    int h = (t >> 3) + it * 32;
    int j = (t & 7) * 8;
    ushort8 val;
#pragma unroll
    for (int e = 0; e < 8; ++e) val[e] = tile[j + e][h];
    *(ushort8*)(vt + ((size_t)b * 256 + h0 + h) * 1024 + j0 + j) = val;
  }
}

// ------------------------------------------------- K1: logits = (QK^T + rel)/16, split-bf16 MFMA
// 64x64 tile, K=256 staged in 2 chunks of 128, frag-ordered LDS (XOR-swizzled), 4 waves
__device__ __forceinline__ int frag_off(int kk, int mt, int ln) {
  return (((((kk << 2) + mt) << 6) + ln) << 4) ^ (kk << 5);   // byte offset, 16 KB array
}

__global__ __launch_bounds__(256) void k1_logits(const float* __restrict__ qg,
                                                 const float* __restrict__ kmat,
                                                 const float* __restrict__ qe,
                                                 float* __restrict__ attn_g) {
  const int b = blockIdx.z, it = blockIdx.y, jt = blockIdx.x;
  const int i0 = it * 64, j0 = jt * 64;
  const int tid = threadIdx.x;
  const int w = tid >> 6, lane = tid & 63;
  const int wm = w >> 1, wn = w & 1;

  __shared__ unsigned short sAh[4 * 4 * 64 * 8];   // 16 KB each, total 64 KB
  __shared__ unsigned short sAl[4 * 4 * 64 * 8];
  __shared__ unsigned short sBh[4 * 4 * 64 * 8];
  __shared__ unsigned short sBl[4 * 4 * 64 * 8];

  f32x4 acc[2][2];
#pragma unroll
  for (int m = 0; m < 2; ++m)
#pragma unroll
    for (int n = 0; n < 2; ++n) acc[m][n] = (f32x4){0.f, 0.f, 0.f, 0.f};

  for (int c = 0; c < 2; ++c) {
    if (c) __syncthreads();
#pragma unroll
    for (int half = 0; half < 2; ++half) {
      const float* src = half ? kmat : qg;
      const int r0 = half ? j0 : i0;
      unsigned short* dh = half ? sBh : sAh;
      unsigned short* dl = half ? sBl : sAl;
#pragma unroll
      for (int itr = 0; itr < 4; ++itr) {
        int id = itr * 256 + tid;
        int row = id >> 4, k8 = id & 15;
        int kglob = c * 128 + k8 * 8;
        int grow = r0 + row;
        float xs[8];
#pragma unroll
        for (int e = 0; e < 8; ++e) xs[e] = 0.f;
        if (grow < L) {
          const float* p = src + ((size_t)b * L + grow) * H + kglob;
          float4a v0 = *(const float4a*)p;
          float4a v1 = *(const float4a*)(p + 4);
          xs[0] = v0.x; xs[1] = v0.y; xs[2] = v0.z; xs[3] = v0.w;
          xs[4] = v1.x; xs[5] = v1.y; xs[6] = v1.z; xs[7] = v1.w;
        }
        ushort8 hi, lo;
#pragma unroll
        for (int e = 0; e < 8; ++e) {
          unsigned short hh = f2bf(xs[e]);
          hi[e] = hh;
          lo[e] = f2bf(xs[e] - bf2f(hh));
        }
        int kk = k8 >> 2, sb = k8 & 3;
        int ln = (row & 15) | (sb << 4);
        int mt = row >> 4;
        int off = frag_off(kk, mt, ln);
        *(ushort8*)((char*)dh + off) = hi;
        *(ushort8*)((char*)dl + off) = lo;
      }
    }
    __syncthreads();
#pragma unroll
    for (int kk = 0; kk < 4; ++kk) {
      short8 ah[2], al[2], bh[2], bl[2];
#pragma unroll
      for (int m = 0; m < 2; ++m) {
        int off = frag_off(kk, wm * 2 + m, lane);
        ah[m] = *(const short8*)((const char*)sAh + off);
        al[m] = *(const short8*)((const char*)sAl + off);
      }
#pragma unroll
      for (int n = 0; n < 2; ++n) {
        int off = frag_off(kk, wn * 2 + n, lane);
        bh[n] = *(const short8*)((const char*)sBh + off);
        bl[n] = *(const short8*)((const char*)sBl + off);
      }
#pragma unroll
      for (int m = 0; m < 2; ++m)
#pragma unroll
        for (int n = 0; n < 2; ++n) {
          acc[m][n] = __builtin_amdgcn_mfma_f32_16x16x32_bf16(ah[m], bh[n], acc[m][n], 0, 0, 0);
          acc[m][n] = __builtin_amdgcn_mfma_f32_16x16x32_bf16(ah[m], bl[n], acc[m][n], 0, 0, 0);
          acc[m][n] = __builtin_amdgcn_mfma_f32_16x16x32_bf16(al[m], bh[n], acc[m][n], 0, 0, 0);
        }
    }
  }
  // epilogue: + rel, /16, store raw logits into attn region
  const int sb = lane >> 4, ln16 = lane & 15;
#pragma unroll
  for (int m = 0; m < 2; ++m)
#pragma unroll
    for (int n = 0; n < 2; ++n)
#pragma unroll
      for (int r = 0; r < 4; ++r) {
        int gi = i0 + wm * 32 + m * 16 + sb * 4 + r;
        int gj = j0 + wn * 32 + n * 16 + ln16;
        if (gi < L && gj < L) {
          int ci = gi / KSHOT, cj = gj / KSHOT;
          int cat = (ci == cj) ? 1 : 2;
          if (gi == gj) cat = 0;
          if (gj == L - 1) cat = 3;
          if (gi == L - 1) cat = (gj == L - 1) ? 5 : 4;
          float lg = (acc[m][n][r] + qe[((size_t)b * L + gi) * 6 + cat]) * 0.0625f;
          attn_g[((size_t)b * L + gi) * L + gj] = lg;
        }
      }
}

// ------------------------------------------------- K2: row softmax (attn out) + PV MFMA (out)
__global__ __launch_bounds__(512) void k2_softmax_pv(const unsigned short* __restrict__ vt,
                                                     float* __restrict__ attn_g,
                                                     float* __restrict__ out_g) {
  const int b = blockIdx.y, it = blockIdx.x;
  const int i0 = it * 32;
  const int tid = threadIdx.x, w = tid >> 6, lane = tid & 63;
  __shared__ unsigned short p_lds[32 * 1024];   // 64 KB, XOR-swizzled bf16 attn tile

  for (int rr = 0; rr < 4; ++rr) {
    const int rl = w * 4 + rr;
    const int gi = i0 + rl;
    const int swz = (rl & 7) << 4;
    if (gi < L) {
      float* lrow = attn_g + ((size_t)b * L + gi) * L;
      float pv[16];
#pragma unroll
      for (int cc = 0; cc < 2; ++cc) {
        const int c = lane + (cc << 6);
        const int j = c << 3;
        if (j + 8 <= L) {
          float4a v0 = *(const float4a*)(lrow + j);
          float4a v1 = *(const float4a*)(lrow + j + 4);
          pv[cc * 8 + 0] = v0.x; pv[cc * 8 + 1] = v0.y; pv[cc * 8 + 2] = v0.z; pv[cc * 8 + 3] = v0.w;
          pv[cc * 8 + 4] = v1.x; pv[cc * 8 + 5] = v1.y; pv[cc * 8 + 6] = v1.z; pv[cc * 8 + 7] = v1.w;
        } else {
#pragma unroll
          for (int e = 0; e < 8; ++e)
            pv[cc * 8 + e] = (j + e < L) ? lrow[j + e] : -3.0e38f;
        }
      }
      float mx = -3.0e38f;
#pragma unroll
      for (int x = 0; x < 16; ++x) mx = fmaxf(mx, pv[x]);
#pragma unroll
      for (int o = 32; o; o >>= 1) mx = fmaxf(mx, __shfl_xor(mx, o, 64));
      float s = 0.f;
#pragma unroll
      for (int x = 0; x < 16; ++x) { pv[x] = __expf(pv[x] - mx); s += pv[x]; }
#pragma unroll
      for (int o = 32; o; o >>= 1) s += __shfl_xor(s, o, 64);
      const float inv_s = 1.f / s;
#pragma unroll
      for (int cc = 0; cc < 2; ++cc) {
        const int c = lane + (cc << 6);
        const int j = c << 3;
        float av[8];
        ushort8 pb;
#pragma unroll
        for (int e = 0; e < 8; ++e) { av[e] = pv[cc * 8 + e] * inv_s; pb[e] = f2bf(av[e]); }
        if (j + 8 <= L) {
          float4a o0 = {av[0], av[1], av[2], av[3]};
          float4a o1 = {av[4], av[5], av[6], av[7]};
          *(float4a*)(lrow + j) = o0;
          *(float4a*)(lrow + j + 4) = o1;
        } else {
#pragma unroll
          for (int e = 0; e < 8; ++e)
            if (j + e < L) lrow[j + e] = av[e];
        }
        int off = ((rl << 11) + (c << 4)) ^ swz;
        *(ushort8*)((char*)p_lds + off) = pb;
      }
    } else {
      ushort8 z = 0;
#pragma unroll
      for (int cc = 0; cc < 2; ++cc) {
        int off = ((rl << 11) + ((lane + (cc << 6)) << 4)) ^ swz;
        *(ushort8*)((char*)p_lds + off) = z;
      }
    }
  }
  __syncthreads();

  f32x4 acc[2][2];
#pragma unroll
  for (int m = 0; m < 2; ++m)
#pragma unroll
    for (int n = 0; n < 2; ++n) acc[m][n] = (f32x4){0.f, 0.f, 0.f, 0.f};
  const int sb = lane >> 4, ln16 = lane & 15;
  for (int ks = 0; ks < 32; ++ks) {
    short8 a[2], bv[2];
#pragma unroll
    for (int m = 0; m < 2; ++m) {
      int row = m * 16 + ln16;
      int off = ((row << 11) + (ks << 6) + (sb << 4)) ^ ((row & 7) << 4);
      a[m] = *(const short8*)((const char*)p_lds + off);
    }
#pragma unroll
    for (int n = 0; n < 2; ++n) {
      int h = w * 32 + n * 16 + ln16;
      bv[n] = *(const short8*)(vt + ((size_t)b * 256 + h) * 1024 + (ks << 5) + (sb << 3));
    }
#pragma unroll
    for (int m = 0; m < 2; ++m)
#pragma unroll
      for (int n = 0; n < 2; ++n)
        acc[m][n] = __builtin_amdgcn_mfma_f32_16x16x32_bf16(a[m], bv[n], acc[m][n], 0, 0, 0);
  }
#pragma unroll
  for (int m = 0; m < 2; ++m)
#pragma unroll
    for (int n = 0; n < 2; ++n)
#pragma unroll
      for (int r = 0; r < 4; ++r) {
        int gi = i0 + m * 16 + sb * 4 + r;
        if (gi < L)
          out_g[((size_t)b * L + gi) * H + w * 32 + n * 16 + ln16] = acc[m][n][r];
      }
}

// ----------------------------------------------------------------------------
extern "C" void kernel_launch(void* const* d_in, const int* in_sizes, int n_in,
                              void* d_out, int out_size, void* d_ws, size_t ws_size,
                              hipStream_t stream) {
  const float* q   = (const float*)d_in[0];
  const float* k   = (const float*)d_in[1];
  const float* v   = (const float*)d_in[2];
  const float* emb = (const float*)d_in[3];
  float* out  = (float*)d_out;
  float* attn = out + (size_t)B_DIM * L * H;

  // ws layout: vt (32*256*1024 bf16 = 16 MB) | qe (32*1001*6 f32 = 0.75 MB)
  unsigned short* vt = (unsigned short*)d_ws;
  float* qe = (float*)((char*)d_ws + (size_t)B_DIM * 256 * 1024 * 2);

  qe_kernel<<<dim3((B_DIM * L) / 4), dim3(256), 0, stream>>>(q, emb, qe);
  vt_kernel<<<dim3(16, 4, B_DIM), dim3(256), 0, stream>>>(v, vt);
  k1_logits<<<dim3(16, 16, B_DIM), dim3(256), 0, stream>>>(q, k, qe, attn);
  k2_softmax_pv<<<dim3(32, B_DIM), dim3(512), 0, stream>>>(vt, attn, out);
}

// Round 2
// 252.476 us; speedup vs baseline: 1.3671x; 1.3671x over previous
//
#include <hip/hip_runtime.h>

#define L     1001
#define H     256
#define B_DIM 32
#define KSHOT 50

typedef float  f32x4   __attribute__((ext_vector_type(4)));
typedef short  short8  __attribute__((ext_vector_type(8)));
typedef unsigned short ushort8 __attribute__((ext_vector_type(8)));
typedef float  float4a __attribute__((ext_vector_type(4), aligned(4)));
typedef _Float16 half8 __attribute__((ext_vector_type(8)));
typedef unsigned short ushort_t;

__device__ __forceinline__ unsigned short f2bf(float x) {
  unsigned int u = __float_as_uint(x);
  u += 0x7FFFu + ((u >> 16) & 1u);           // RNE
  return (unsigned short)(u >> 16);
}
__device__ __forceinline__ float bf2f(unsigned short h) {
  return __uint_as_float(((unsigned int)h) << 16);
}

__device__ __forceinline__ void async_copy16(const void* g, void* l) {
  __builtin_amdgcn_global_load_lds(
      (const __attribute__((address_space(1))) void*)g,
      (__attribute__((address_space(3))) void*)l, 16, 0, 0);
}

// ---------------------------------------------------------------- qe: q . emb
__global__ __launch_bounds__(256) void qe_kernel(const float* __restrict__ q,
                                                 const float* __restrict__ emb,
                                                 float* __restrict__ qe) {
  int wid  = (blockIdx.x << 2) + (threadIdx.x >> 6);
  int lane = threadIdx.x & 63;
  if (wid >= B_DIM * L) return;
  const float4a qv = *(const float4a*)(q + (size_t)wid * H + lane * 4);
  float acc[6];
#pragma unroll
  for (int c = 0; c < 6; ++c) {
    float4a ev = *(const float4a*)(emb + c * H + lane * 4);
    acc[c] = qv.x * ev.x + qv.y * ev.y + qv.z * ev.z + qv.w * ev.w;
  }
#pragma unroll
  for (int c = 0; c < 6; ++c)
#pragma unroll
    for (int o = 32; o; o >>= 1) acc[c] += __shfl_xor(acc[c], o, 64);
  if (lane == 0) {
    float* dst = qe + (size_t)wid * 6;
    dst[0] = acc[0]; dst[1] = acc[1]; dst[2] = acc[2];
    dst[3] = acc[3]; dst[4] = acc[4]; dst[5] = acc[5];
  }
}

// ------------------------------------------------- v -> vt[b][h][j] bf16 (j padded to 1024)
__global__ __launch_bounds__(256) void vt_kernel(const float* __restrict__ v,
                                                 ushort_t* __restrict__ vt) {
  const int b = blockIdx.z, ht = blockIdx.y, jt = blockIdx.x;
  const int j0 = jt * 64, h0 = ht * 64;
  const int t = threadIdx.x;
  __shared__ ushort_t tile[64][68];
#pragma unroll
  for (int it = 0; it < 4; ++it) {
    int j = (t >> 4) + it * 16;
    int h = (t & 15) * 4;
    int gj = j0 + j;
    float4a val = {0.f, 0.f, 0.f, 0.f};
    if (gj < L) val = *(const float4a*)(v + ((size_t)b * L + gj) * H + h0 + h);
    tile[j][h + 0] = f2bf(val.x);
    tile[j][h + 1] = f2bf(val.y);
    tile[j][h + 2] = f2bf(val.z);
    tile[j][h + 3] = f2bf(val.w);
  }
  __syncthreads();
#pragma unroll
  for (int it = 0; it < 2; ++it) {
    int h = (t >> 3) + it * 32;
    int j = (t & 7) * 8;
    ushort8 val;
#pragma unroll
    for (int e = 0; e < 8; ++e) val[e] = tile[j + e][h];
    *(ushort8*)(vt + ((size_t)b * 256 + h0 + h) * 1024 + j0 + j) = val;
  }
}

// ------------------------------------------------- split q/k -> hi/lo bf16 in fragment granules
// granule (b, pg, kk): 16 rows x 32 k; lane holds row=lane&15, k=kk*32+(lane>>4)*8+e
// storage: gid = (b*64+pg)*8+kk ; granule at gid*512 ushorts, lane at +lane*8
__global__ __launch_bounds__(256) void split_kernel(const float* __restrict__ src,
                                                    ushort_t* __restrict__ hi,
                                                    ushort_t* __restrict__ lo) {
  const int gid  = blockIdx.x * 4 + (threadIdx.x >> 6);   // 0 .. 16383
  const int lane = threadIdx.x & 63;
  const int kk = gid & 7, pg = (gid >> 3) & 63, b = gid >> 9;
  const int row = pg * 16 + (lane & 15);
  const int col = kk * 32 + (lane >> 4) * 8;
  float xs[8];
#pragma unroll
  for (int e = 0; e < 8; ++e) xs[e] = 0.f;
  if (row < L) {
    const float* p = src + ((size_t)b * L + row) * H + col;
    float4a v0 = *(const float4a*)p;
    float4a v1 = *(const float4a*)(p + 4);
    xs[0] = v0.x; xs[1] = v0.y; xs[2] = v0.z; xs[3] = v0.w;
    xs[4] = v1.x; xs[5] = v1.y; xs[6] = v1.z; xs[7] = v1.w;
  }
  ushort8 h8, l8;
#pragma unroll
  for (int e = 0; e < 8; ++e) {
    unsigned short hh = f2bf(xs[e]);
    h8[e] = hh;
    l8[e] = f2bf(xs[e] - bf2f(hh));
  }
  size_t dst = ((size_t)gid << 9) + lane * 8;
  *(ushort8*)(hi + dst) = h8;
  *(ushort8*)(lo + dst) = l8;
}

// ------------------------------------------------- K1: 128x128 tile split-bf16 GEMM, BK=32 dbuf
// logits = (QK^T + rel)/16 ; LG16 ? fp16 -> lg[b][1024][1024] : fp32 -> attn[b][L][L]
template <int LG16>
__global__ __launch_bounds__(256, 2) void k1_gemm(const ushort_t* __restrict__ qh,
                                                  const ushort_t* __restrict__ ql,
                                                  const ushort_t* __restrict__ kh,
                                                  const ushort_t* __restrict__ kl,
                                                  const float* __restrict__ qe,
                                                  float* __restrict__ attn_g,
                                                  _Float16* __restrict__ lg) {
  const int b = blockIdx.z, it = blockIdx.y, jt = blockIdx.x;
  const int i0 = it * 128, j0 = jt * 128;
  const int tid = threadIdx.x;
  const int w = tid >> 6, lane = tid & 63;
  const int wm = w >> 1, wn = w & 1;

  __shared__ ushort_t lds[2][32][512];   // 64 KB: [buf][granule: a*8+p][512 ushorts]

  // wave w stages array w: 0=qh 1=ql 2=kh 3=kl
  const ushort_t* base = (w == 0) ? qh : (w == 1) ? ql : (w == 2) ? kh : kl;
  const int pan0 = (w < 2) ? (i0 >> 4) : (j0 >> 4);
  const ushort_t* gsrc0 = base + (((size_t)b * 64 + pan0) * 8) * 512 + lane * 8;

#define K1_STAGE(c_, buf_)                                        \
  _Pragma("unroll") for (int t = 0; t < 8; ++t)                   \
      async_copy16(gsrc0 + (size_t)(c_) * 512 + (size_t)t * 4096, \
                   &lds[buf_][w * 8 + t][0]);

  f32x4 acc[4][4];
#pragma unroll
  for (int m = 0; m < 4; ++m)
#pragma unroll
    for (int n = 0; n < 4; ++n) acc[m][n] = (f32x4){0.f, 0.f, 0.f, 0.f};

  K1_STAGE(0, 0);
  asm volatile("s_waitcnt vmcnt(0)" ::: "memory");
  __syncthreads();

  for (int c = 0; c < 8; ++c) {
    const int buf = c & 1;
    if (c < 7) { K1_STAGE(c + 1, buf ^ 1); }
    short8 ah[4], al[4], bh[4], bl[4];
#pragma unroll
    for (int m = 0; m < 4; ++m) {
      ah[m] = *(const short8*)&lds[buf][0 * 8 + wm * 4 + m][(size_t)lane * 8];
      al[m] = *(const short8*)&lds[buf][1 * 8 + wm * 4 + m][(size_t)lane * 8];
    }
#pragma unroll
    for (int n = 0; n < 4; ++n) {
      bh[n] = *(const short8*)&lds[buf][2 * 8 + wn * 4 + n][(size_t)lane * 8];
      bl[n] = *(const short8*)&lds[buf][3 * 8 + wn * 4 + n][(size_t)lane * 8];
    }
#pragma unroll
    for (int m = 0; m < 4; ++m)
#pragma unroll
      for (int n = 0; n < 4; ++n) {
        acc[m][n] = __builtin_amdgcn_mfma_f32_16x16x32_bf16(ah[m], bh[n], acc[m][n], 0, 0, 0);
        acc[m][n] = __builtin_amdgcn_mfma_f32_16x16x32_bf16(ah[m], bl[n], acc[m][n], 0, 0, 0);
        acc[m][n] = __builtin_amdgcn_mfma_f32_16x16x32_bf16(al[m], bh[n], acc[m][n], 0, 0, 0);
      }
    asm volatile("s_waitcnt vmcnt(0)" ::: "memory");
    __syncthreads();
  }
#undef K1_STAGE

  const int sb = lane >> 4, ln16 = lane & 15;
#pragma unroll
  for (int m = 0; m < 4; ++m)
#pragma unroll
    for (int n = 0; n < 4; ++n) {
      const int gj = j0 + wn * 64 + n * 16 + ln16;
#pragma unroll
      for (int r = 0; r < 4; ++r) {
        const int gi = i0 + wm * 64 + m * 16 + sb * 4 + r;
        const bool in = (gi < L) & (gj < L);
        float bias = 0.f;
        if (in) {
          int ci = gi / KSHOT, cj = gj / KSHOT;
          int cat = (ci == cj) ? 1 : 2;
          if (gi == gj) cat = 0;
          if (gj == L - 1) cat = 3;
          if (gi == L - 1) cat = (gj == L - 1) ? 5 : 4;
          bias = qe[((size_t)b * L + gi) * 6 + cat];
        }
        float val = (acc[m][n][r] + bias) * 0.0625f;
        if (LG16) {
          lg[((size_t)b << 20) + ((size_t)gi << 10) + gj] = (_Float16)val;
        } else if (in) {
          attn_g[((size_t)b * L + gi) * L + gj] = val;
        }
      }
    }
}

// ------------------------------------------------- K2: row softmax (attn out) + PV MFMA (out)
template <int LG16>
__global__ __launch_bounds__(512) void k2_softmax_pv(const ushort_t* __restrict__ vt,
                                                     const _Float16* __restrict__ lg,
                                                     float* __restrict__ attn_g,
                                                     float* __restrict__ out_g) {
  const int b = blockIdx.y, it = blockIdx.x;
  const int i0 = it * 32;
  const int tid = threadIdx.x, w = tid >> 6, lane = tid & 63;
  __shared__ ushort_t p_lds[32 * 1024];   // 64 KB, XOR-swizzled bf16 attn tile

  for (int rr = 0; rr < 4; ++rr) {
    const int rl = w * 4 + rr;
    const int gi = i0 + rl;
    const int swz = (rl & 7) << 4;
    if (gi < L) {
      float* arow = attn_g + ((size_t)b * L + gi) * L;
      float pv[16];
      if (LG16) {
        const _Float16* lrow = lg + ((size_t)b << 20) + ((size_t)gi << 10);
#pragma unroll
        for (int cc = 0; cc < 2; ++cc) {
          const int j = (lane + (cc << 6)) << 3;
          half8 hv = *(const half8*)(lrow + j);
#pragma unroll
          for (int e = 0; e < 8; ++e)
            pv[cc * 8 + e] = (j + e < L) ? (float)hv[e] : -3.0e38f;
        }
      } else {
#pragma unroll
        for (int cc = 0; cc < 2; ++cc) {
          const int j = (lane + (cc << 6)) << 3;
          if (j + 8 <= L) {
            float4a v0 = *(const float4a*)(arow + j);
            float4a v1 = *(const float4a*)(arow + j + 4);
            pv[cc * 8 + 0] = v0.x; pv[cc * 8 + 1] = v0.y; pv[cc * 8 + 2] = v0.z; pv[cc * 8 + 3] = v0.w;
            pv[cc * 8 + 4] = v1.x; pv[cc * 8 + 5] = v1.y; pv[cc * 8 + 6] = v1.z; pv[cc * 8 + 7] = v1.w;
          } else {
#pragma unroll
            for (int e = 0; e < 8; ++e)
              pv[cc * 8 + e] = (j + e < L) ? arow[j + e] : -3.0e38f;
          }
        }
      }
      float mx = -3.0e38f;
#pragma unroll
      for (int x = 0; x < 16; ++x) mx = fmaxf(mx, pv[x]);
#pragma unroll
      for (int o = 32; o; o >>= 1) mx = fmaxf(mx, __shfl_xor(mx, o, 64));
      float s = 0.f;
#pragma unroll
      for (int x = 0; x < 16; ++x) { pv[x] = __expf(pv[x] - mx); s += pv[x]; }
#pragma unroll
      for (int o = 32; o; o >>= 1) s += __shfl_xor(s, o, 64);
      const float inv_s = 1.f / s;
#pragma unroll
      for (int cc = 0; cc < 2; ++cc) {
        const int c = lane + (cc << 6);
        const int j = c << 3;
        float av[8];
        ushort8 pb;
#pragma unroll
        for (int e = 0; e < 8; ++e) { av[e] = pv[cc * 8 + e] * inv_s; pb[e] = f2bf(av[e]); }
        if (j + 8 <= L) {
          float4a o0 = {av[0], av[1], av[2], av[3]};
          float4a o1 = {av[4], av[5], av[6], av[7]};
          *(float4a*)(arow + j) = o0;
          *(float4a*)(arow + j + 4) = o1;
        } else {
#pragma unroll
          for (int e = 0; e < 8; ++e)
            if (j + e < L) arow[j + e] = av[e];
        }
        int off = ((rl << 11) + (c << 4)) ^ swz;
        *(ushort8*)((char*)p_lds + off) = pb;
      }
    } else {
      ushort8 z = 0;
#pragma unroll
      for (int cc = 0; cc < 2; ++cc) {
        int off = ((rl << 11) + ((lane + (cc << 6)) << 4)) ^ swz;
        *(ushort8*)((char*)p_lds + off) = z;
      }
    }
  }
  __syncthreads();

  f32x4 acc[2][2];
#pragma unroll
  for (int m = 0; m < 2; ++m)
#pragma unroll
    for (int n = 0; n < 2; ++n) acc[m][n] = (f32x4){0.f, 0.f, 0.f, 0.f};
  const int sb = lane >> 4, ln16 = lane & 15;
  for (int ks = 0; ks < 32; ++ks) {
    short8 a[2], bv[2];
#pragma unroll
    for (int m = 0; m < 2; ++m) {
      int row = m * 16 + ln16;
      int off = ((row << 11) + (ks << 6) + (sb << 4)) ^ ((row & 7) << 4);
      a[m] = *(const short8*)((const char*)p_lds + off);
    }
#pragma unroll
    for (int n = 0; n < 2; ++n) {
      int h = w * 32 + n * 16 + ln16;
      bv[n] = *(const short8*)(vt + ((size_t)b * 256 + h) * 1024 + (ks << 5) + (sb << 3));
    }
#pragma unroll
    for (int m = 0; m < 2; ++m)
#pragma unroll
      for (int n = 0; n < 2; ++n)
        acc[m][n] = __builtin_amdgcn_mfma_f32_16x16x32_bf16(a[m], bv[n], acc[m][n], 0, 0, 0);
  }
#pragma unroll
  for (int m = 0; m < 2; ++m)
#pragma unroll
    for (int n = 0; n < 2; ++n)
#pragma unroll
      for (int r = 0; r < 4; ++r) {
        int gi = i0 + m * 16 + sb * 4 + r;
        if (gi < L)
          out_g[((size_t)b * L + gi) * H + w * 32 + n * 16 + ln16] = acc[m][n][r];
      }
}

// ------------------------------------------------- legacy K1 (round-1, in-kernel split) fallback
__device__ __forceinline__ int frag_off(int kk, int mt, int ln) {
  return (((((kk << 2) + mt) << 6) + ln) << 4) ^ (kk << 5);
}

__global__ __launch_bounds__(256) void k1_legacy(const float* __restrict__ qg,
                                                 const float* __restrict__ kmat,
                                                 const float* __restrict__ qe,
                                                 float* __restrict__ attn_g) {
  const int b = blockIdx.z, it = blockIdx.y, jt = blockIdx.x;
  const int i0 = it * 64, j0 = jt * 64;
  const int tid = threadIdx.x;
  const int w = tid >> 6, lane = tid & 63;
  const int wm = w >> 1, wn = w & 1;

  __shared__ ushort_t sAh[4 * 4 * 64 * 8];
  __shared__ ushort_t sAl[4 * 4 * 64 * 8];
  __shared__ ushort_t sBh[4 * 4 * 64 * 8];
  __shared__ ushort_t sBl[4 * 4 * 64 * 8];

  f32x4 acc[2][2];
#pragma unroll
  for (int m = 0; m < 2; ++m)
#pragma unroll
    for (int n = 0; n < 2; ++n) acc[m][n] = (f32x4){0.f, 0.f, 0.f, 0.f};

  for (int c = 0; c < 2; ++c) {
    if (c) __syncthreads();
#pragma unroll
    for (int half = 0; half < 2; ++half) {
      const float* src = half ? kmat : qg;
      const int r0 = half ? j0 : i0;
      ushort_t* dh = half ? sBh : sAh;
      ushort_t* dl = half ? sBl : sAl;
#pragma unroll
      for (int itr = 0; itr < 4; ++itr) {
        int id = itr * 256 + tid;
        int row = id >> 4, k8 = id & 15;
        int kglob = c * 128 + k8 * 8;
        int grow = r0 + row;
        float xs[8];
#pragma unroll
        for (int e = 0; e < 8; ++e) xs[e] = 0.f;
        if (grow < L) {
          const float* p = src + ((size_t)b * L + grow) * H + kglob;
          float4a v0 = *(const float4a*)p;
          float4a v1 = *(const float4a*)(p + 4);
          xs[0] = v0.x; xs[1] = v0.y; xs[2] = v0.z; xs[3] = v0.w;
          xs[4] = v1.x; xs[5] = v1.y; xs[6] = v1.z; xs[7] = v1.w;
        }
        ushort8 hi, lo;
#pragma unroll
        for (int e = 0; e < 8; ++e) {
          unsigned short hh = f2bf(xs[e]);
          hi[e] = hh;
          lo[e] = f2bf(xs[e] - bf2f(hh));
        }
        int kk = k8 >> 2, sbb = k8 & 3;
        int ln = (row & 15) | (sbb << 4);
        int mt = row >> 4;
        int off = frag_off(kk, mt, ln);
        *(ushort8*)((char*)dh + off) = hi;
        *(ushort8*)((char*)dl + off) = lo;
      }
    }
    __syncthreads();
#pragma unroll
    for (int kk = 0; kk < 4; ++kk) {
      short8 ah[2], al[2], bh[2], bl[2];
#pragma unroll
      for (int m = 0; m < 2; ++m) {
        int off = frag_off(kk, wm * 2 + m, lane);
        ah[m] = *(const short8*)((const char*)sAh + off);
        al[m] = *(const short8*)((const char*)sAl + off);
      }
#pragma unroll
      for (int n = 0; n < 2; ++n) {
        int off = frag_off(kk, wn * 2 + n, lane);
        bh[n] = *(const short8*)((const char*)sBh + off);
        bl[n] = *(const short8*)((const char*)sBl + off);
      }
#pragma unroll
      for (int m = 0; m < 2; ++m)
#pragma unroll
        for (int n = 0; n < 2; ++n) {
          acc[m][n] = __builtin_amdgcn_mfma_f32_16x16x32_bf16(ah[m], bh[n], acc[m][n], 0, 0, 0);
          acc[m][n] = __builtin_amdgcn_mfma_f32_16x16x32_bf16(ah[m], bl[n], acc[m][n], 0, 0, 0);
          acc[m][n] = __builtin_amdgcn_mfma_f32_16x16x32_bf16(al[m], bh[n], acc[m][n], 0, 0, 0);
        }
    }
  }
  const int sb = lane >> 4, ln16 = lane & 15;
#pragma unroll
  for (int m = 0; m < 2; ++m)
#pragma unroll
    for (int n = 0; n < 2; ++n)
#pragma unroll
      for (int r = 0; r < 4; ++r) {
        int gi = i0 + wm * 32 + m * 16 + sb * 4 + r;
        int gj = j0 + wn * 32 + n * 16 + ln16;
        if (gi < L && gj < L) {
          int ci = gi / KSHOT, cj = gj / KSHOT;
          int cat = (ci == cj) ? 1 : 2;
          if (gi == gj) cat = 0;
          if (gj == L - 1) cat = 3;
          if (gi == L - 1) cat = (gj == L - 1) ? 5 : 4;
          float lgv = (acc[m][n][r] + qe[((size_t)b * L + gi) * 6 + cat]) * 0.0625f;
          attn_g[((size_t)b * L + gi) * L + gj] = lgv;
        }
      }
}

// ----------------------------------------------------------------------------
extern "C" void kernel_launch(void* const* d_in, const int* in_sizes, int n_in,
                              void* d_out, int out_size, void* d_ws, size_t ws_size,
                              hipStream_t stream) {
  const float* q   = (const float*)d_in[0];
  const float* k   = (const float*)d_in[1];
  const float* v   = (const float*)d_in[2];
  const float* emb = (const float*)d_in[3];
  float* out  = (float*)d_out;
  float* attn = out + (size_t)B_DIM * L * H;

  const size_t VT = 16777216, QE = 1048576, SP = 16777216;
  const size_t BASE = VT + QE + 4 * SP;        // 84,934,656
  const size_t FULL = BASE + 67108864;         // 152,043,520

  char* wsp = (char*)d_ws;
  ushort_t* vt = (ushort_t*)wsp;
  float*    qe = (float*)(wsp + VT);
  ushort_t* qh = (ushort_t*)(wsp + VT + QE);
  ushort_t* ql = qh + SP / 2;
  ushort_t* kh = ql + SP / 2;
  ushort_t* kl = kh + SP / 2;
  _Float16* lg = (_Float16*)(wsp + BASE);

  qe_kernel<<<dim3((B_DIM * L) / 4), dim3(256), 0, stream>>>(q, emb, qe);
  vt_kernel<<<dim3(16, 4, B_DIM), dim3(256), 0, stream>>>(v, vt);

  if (ws_size >= FULL) {
    split_kernel<<<dim3(4096), dim3(256), 0, stream>>>(q, qh, ql);
    split_kernel<<<dim3(4096), dim3(256), 0, stream>>>(k, kh, kl);
    k1_gemm<1><<<dim3(8, 8, B_DIM), dim3(256), 0, stream>>>(qh, ql, kh, kl, qe, nullptr, lg);
    k2_softmax_pv<1><<<dim3(32, B_DIM), dim3(512), 0, stream>>>(vt, lg, attn, out);
  } else if (ws_size >= BASE) {
    split_kernel<<<dim3(4096), dim3(256), 0, stream>>>(q, qh, ql);
    split_kernel<<<dim3(4096), dim3(256), 0, stream>>>(k, kh, kl);
    k1_gemm<0><<<dim3(8, 8, B_DIM), dim3(256), 0, stream>>>(qh, ql, kh, kl, qe, attn, nullptr);
    k2_softmax_pv<0><<<dim3(32, B_DIM), dim3(512), 0, stream>>>(vt, nullptr, attn, out);
  } else {
    k1_legacy<<<dim3(16, 16, B_DIM), dim3(256), 0, stream>>>(q, k, qe, attn);
    k2_softmax_pv<0><<<dim3(32, B_DIM), dim3(512), 0, stream>>>(vt, nullptr, attn, out);
  }
}

// Round 3
// 197.016 us; speedup vs baseline: 1.7520x; 1.2815x over previous
//
#include <hip/hip_runtime.h>

#define L     1001
#define H     256
#define B_DIM 32
#define KSHOT 50

typedef float  f32x4   __attribute__((ext_vector_type(4)));
typedef short  short8  __attribute__((ext_vector_type(8)));
typedef unsigned short ushort8 __attribute__((ext_vector_type(8)));
typedef float  float4a __attribute__((ext_vector_type(4), aligned(4)));
typedef _Float16 half8 __attribute__((ext_vector_type(8)));
typedef unsigned short ushort_t;

__device__ __forceinline__ unsigned short f2bf(float x) {
  unsigned int u = __float_as_uint(x);
  u += 0x7FFFu + ((u >> 16) & 1u);           // RNE
  return (unsigned short)(u >> 16);
}
__device__ __forceinline__ float bf2f(unsigned short h) {
  return __uint_as_float(((unsigned int)h) << 16);
}

__device__ __forceinline__ void async_copy16(const void* g, void* l) {
  __builtin_amdgcn_global_load_lds(
      (const __attribute__((address_space(1))) void*)g,
      (__attribute__((address_space(3))) void*)l, 16, 0, 0);
}

// ---------------------------------------------------------------- qe: q . emb
__global__ __launch_bounds__(256) void qe_kernel(const float* __restrict__ q,
                                                 const float* __restrict__ emb,
                                                 float* __restrict__ qe) {
  int wid  = (blockIdx.x << 2) + (threadIdx.x >> 6);
  int lane = threadIdx.x & 63;
  if (wid >= B_DIM * L) return;
  const float4a qv = *(const float4a*)(q + (size_t)wid * H + lane * 4);
  float acc[6];
#pragma unroll
  for (int c = 0; c < 6; ++c) {
    float4a ev = *(const float4a*)(emb + c * H + lane * 4);
    acc[c] = qv.x * ev.x + qv.y * ev.y + qv.z * ev.z + qv.w * ev.w;
  }
#pragma unroll
  for (int c = 0; c < 6; ++c)
#pragma unroll
    for (int o = 32; o; o >>= 1) acc[c] += __shfl_xor(acc[c], o, 64);
  if (lane == 0) {
    float* dst = qe + (size_t)wid * 6;
    dst[0] = acc[0]; dst[1] = acc[1]; dst[2] = acc[2];
    dst[3] = acc[3]; dst[4] = acc[4]; dst[5] = acc[5];
  }
}

// ------------------------------------------------- v -> vt[b][h][j] bf16 (j padded to 1024)
__global__ __launch_bounds__(256) void vt_kernel(const float* __restrict__ v,
                                                 ushort_t* __restrict__ vt) {
  const int b = blockIdx.z, ht = blockIdx.y, jt = blockIdx.x;
  const int j0 = jt * 64, h0 = ht * 64;
  const int t = threadIdx.x;
  __shared__ ushort_t tile[64][68];
#pragma unroll
  for (int it = 0; it < 4; ++it) {
    int j = (t >> 4) + it * 16;
    int h = (t & 15) * 4;
    int gj = j0 + j;
    float4a val = {0.f, 0.f, 0.f, 0.f};
    if (gj < L) val = *(const float4a*)(v + ((size_t)b * L + gj) * H + h0 + h);
    tile[j][h + 0] = f2bf(val.x);
    tile[j][h + 1] = f2bf(val.y);
    tile[j][h + 2] = f2bf(val.z);
    tile[j][h + 3] = f2bf(val.w);
  }
  __syncthreads();
#pragma unroll
  for (int it = 0; it < 2; ++it) {
    int h = (t >> 3) + it * 32;
    int j = (t & 7) * 8;
    ushort8 val;
#pragma unroll
    for (int e = 0; e < 8; ++e) val[e] = tile[j + e][h];
    *(ushort8*)(vt + ((size_t)b * 256 + h0 + h) * 1024 + j0 + j) = val;
  }
}

// ------------------------------------------------- convert q,k -> bf16 fragment granules
// granule (b, pg, kk): 16 rows x 32 k; lane: row=pg*16+(l&15), k=kk*32+(l>>4)*8+e
__global__ __launch_bounds__(256) void convert_kernel(const float* __restrict__ q,
                                                      const float* __restrict__ k,
                                                      ushort_t* __restrict__ qb,
                                                      ushort_t* __restrict__ kb) {
  const int gid  = blockIdx.x * 4 + (threadIdx.x >> 6);   // 0 .. 32767
  const int lane = threadIdx.x & 63;
  const int mat = gid >> 14;
  const int g = gid & 16383;
  const int kk = g & 7, pg = (g >> 3) & 63, b = g >> 9;
  const int row = pg * 16 + (lane & 15);
  const int col = kk * 32 + (lane >> 4) * 8;
  const float* src = mat ? k : q;
  ushort_t* dst = mat ? kb : qb;
  float xs[8];
#pragma unroll
  for (int e = 0; e < 8; ++e) xs[e] = 0.f;
  if (row < L) {
    const float* p = src + ((size_t)b * L + row) * H + col;
    float4a v0 = *(const float4a*)p;
    float4a v1 = *(const float4a*)(p + 4);
    xs[0] = v0.x; xs[1] = v0.y; xs[2] = v0.z; xs[3] = v0.w;
    xs[4] = v1.x; xs[5] = v1.y; xs[6] = v1.z; xs[7] = v1.w;
  }
  ushort8 h8;
#pragma unroll
  for (int e = 0; e < 8; ++e) h8[e] = f2bf(xs[e]);
  *(ushort8*)(dst + ((size_t)g << 9) + lane * 8) = h8;
}

// ------------------------------------------------- K1: 128x128 bf16 GEMM, BK=32 dbuf, fp16 logits
__global__ __launch_bounds__(256, 4) void k1_gemm(const ushort_t* __restrict__ qb,
                                                  const ushort_t* __restrict__ kb,
                                                  const float* __restrict__ qe,
                                                  _Float16* __restrict__ lg) {
  const int bid = blockIdx.x;
  const int bs = (bid & 7) * 256 + (bid >> 3);    // XCD-chunked swizzle (2048 % 8 == 0)
  const int jt = bs & 7, it = (bs >> 3) & 7, b = bs >> 6;
  const int i0 = it * 128, j0 = jt * 128;
  const int tid = threadIdx.x;
  const int w = tid >> 6, lane = tid & 63;
  const int wm = w >> 1, wn = w & 1;

  __shared__ ushort_t lds[2][16][512];   // 32 KB

  const ushort_t* base = (w < 2) ? qb : kb;
  const int pg0 = ((w < 2) ? it : jt) * 8 + (w & 1) * 4;
  const ushort_t* gsrc0 = base + ((size_t)(b * 64 + pg0) * 8) * 512 + lane * 8;

#define K1_STAGE(c_, buf_)                                        \
  _Pragma("unroll") for (int t = 0; t < 4; ++t)                   \
      async_copy16(gsrc0 + (size_t)(c_) * 512 + (size_t)t * 4096, \
                   &lds[buf_][w * 4 + t][0]);

  f32x4 acc[4][4];
#pragma unroll
  for (int m = 0; m < 4; ++m)
#pragma unroll
    for (int n = 0; n < 4; ++n) acc[m][n] = (f32x4){0.f, 0.f, 0.f, 0.f};

  K1_STAGE(0, 0);
  asm volatile("s_waitcnt vmcnt(0)" ::: "memory");
  __syncthreads();

  for (int c = 0; c < 8; ++c) {
    const int buf = c & 1;
    if (c < 7) { K1_STAGE(c + 1, buf ^ 1); }
    short8 av[4], bv[4];
#pragma unroll
    for (int m = 0; m < 4; ++m)
      av[m] = *(const short8*)&lds[buf][wm * 4 + m][(size_t)lane * 8];
#pragma unroll
    for (int n = 0; n < 4; ++n)
      bv[n] = *(const short8*)&lds[buf][8 + wn * 4 + n][(size_t)lane * 8];
#pragma unroll
    for (int m = 0; m < 4; ++m)
#pragma unroll
      for (int n = 0; n < 4; ++n)
        acc[m][n] = __builtin_amdgcn_mfma_f32_16x16x32_bf16(av[m], bv[n], acc[m][n], 0, 0, 0);
    asm volatile("s_waitcnt vmcnt(0)" ::: "memory");
    __syncthreads();
  }
#undef K1_STAGE

  const int sb = lane >> 4, ln16 = lane & 15;
#pragma unroll
  for (int m = 0; m < 4; ++m)
#pragma unroll
    for (int n = 0; n < 4; ++n) {
      const int gj = j0 + wn * 64 + n * 16 + ln16;
#pragma unroll
      for (int r = 0; r < 4; ++r) {
        const int gi = i0 + wm * 64 + m * 16 + sb * 4 + r;
        float bias = 0.f;
        if ((gi < L) & (gj < L)) {
          int ci = gi / KSHOT, cj = gj / KSHOT;
          int cat = (ci == cj) ? 1 : 2;
          if (gi == gj) cat = 0;
          if (gj == L - 1) cat = 3;
          if (gi == L - 1) cat = (gj == L - 1) ? 5 : 4;
          bias = qe[((size_t)b * L + gi) * 6 + cat];
        }
        lg[((size_t)b << 20) + ((size_t)gi << 10) + gj] =
            (_Float16)((acc[m][n][r] + bias) * 0.0625f);
      }
    }
}

// ------------------------------------------------- K2: softmax + attn store + PV MFMA
// P in LDS as granules: g = (row>>4)*32 + (j>>5); within granule slot s = ((row&15)|(((j>>3)&3)<<4)) ^ (g&7)
__global__ __launch_bounds__(512, 4) void k2_softmax_pv(const ushort_t* __restrict__ vt,
                                                        const _Float16* __restrict__ lg,
                                                        float* __restrict__ attn_g,
                                                        float* __restrict__ out_g) {
  const int bid = blockIdx.x;
  const int bs = (bid & 7) * 128 + (bid >> 3);    // XCD-chunked swizzle (1024 % 8 == 0)
  const int b = bs >> 5, it = bs & 31;
  const int i0 = it * 32;
  const int tid = threadIdx.x, w = tid >> 6, lane = tid & 63;
  __shared__ ushort_t p_lds[64 * 512];   // 64 KB, 64 granules of 1 KB

  // ---- phase A: load fp16 logits, row softmax, P(bf16) -> granule LDS
#pragma unroll
  for (int rr = 0; rr < 4; ++rr) {
    const int rl = w * 4 + rr;
    const int gi = i0 + rl;
    if (gi < L) {
      const _Float16* lrow = lg + ((size_t)b << 20) + ((size_t)gi << 10);
      float pv[16];
#pragma unroll
      for (int cc = 0; cc < 2; ++cc) {
        const int j = (lane + (cc << 6)) << 3;
        half8 hv = *(const half8*)(lrow + j);
#pragma unroll
        for (int e = 0; e < 8; ++e)
          pv[cc * 8 + e] = (j + e < L) ? (float)hv[e] : -3.0e38f;
      }
      float mx = -3.0e38f;
#pragma unroll
      for (int x = 0; x < 16; ++x) mx = fmaxf(mx, pv[x]);
#pragma unroll
      for (int o = 32; o; o >>= 1) mx = fmaxf(mx, __shfl_xor(mx, o, 64));
      float s = 0.f;
#pragma unroll
      for (int x = 0; x < 16; ++x) { pv[x] = __expf(pv[x] - mx); s += pv[x]; }
#pragma unroll
      for (int o = 32; o; o >>= 1) s += __shfl_xor(s, o, 64);
      const float inv_s = 1.f / s;
#pragma unroll
      for (int cc = 0; cc < 2; ++cc) {
        const int c = lane + (cc << 6);
        ushort8 pb;
#pragma unroll
        for (int e = 0; e < 8; ++e) pb[e] = f2bf(pv[cc * 8 + e] * inv_s);
        const int g = ((rl >> 4) << 5) + (c >> 2);
        const int slot = ((rl & 15) | ((c & 3) << 4)) ^ (g & 7);
        *(ushort8*)((char*)p_lds + g * 1024 + slot * 16) = pb;
      }
    } else {
      ushort8 z = 0;
#pragma unroll
      for (int cc = 0; cc < 2; ++cc) {
        const int c = lane + (cc << 6);
        const int g = ((rl >> 4) << 5) + (c >> 2);
        const int slot = ((rl & 15) | ((c & 3) << 4)) ^ (g & 7);
        *(ushort8*)((char*)p_lds + g * 1024 + slot * 16) = z;
      }
    }
  }
  __syncthreads();

  // ---- phase C (issued early so stores overlap PV): attn fp32 from bf16 P
#pragma unroll
  for (int rr = 0; rr < 4; ++rr) {
    const int rl = w * 4 + rr;
    const int gi = i0 + rl;
    if (gi < L) {
      float* arow = attn_g + ((size_t)b * L + gi) * L;
#pragma unroll
      for (int cc = 0; cc < 2; ++cc) {
        const int c = lane + (cc << 6);
        const int g = ((rl >> 4) << 5) + (c >> 2);
        const int slot = ((rl & 15) | ((c & 3) << 4)) ^ (g & 7);
        ushort8 pb = *(const ushort8*)((const char*)p_lds + g * 1024 + slot * 16);
        const int j = c << 3;
        if (j + 8 <= L) {
          float4a o0 = {bf2f(pb[0]), bf2f(pb[1]), bf2f(pb[2]), bf2f(pb[3])};
          float4a o1 = {bf2f(pb[4]), bf2f(pb[5]), bf2f(pb[6]), bf2f(pb[7])};
          *(float4a*)(arow + j) = o0;
          *(float4a*)(arow + j + 4) = o1;
        } else {
#pragma unroll
          for (int e = 0; e < 8; ++e)
            if (j + e < L) arow[j + e] = bf2f(pb[e]);
        }
      }
    }
  }

  // ---- phase B: PV MFMA with vt prefetch
  f32x4 acc[2][2];
#pragma unroll
  for (int m = 0; m < 2; ++m)
#pragma unroll
    for (int n = 0; n < 2; ++n) acc[m][n] = (f32x4){0.f, 0.f, 0.f, 0.f};
  const int sb = lane >> 4, ln16 = lane & 15;
  const ushort_t* vrow0 = vt + ((size_t)b * 256 + w * 32 + ln16) * 1024 + sb * 8;

  short8 bn[2];
#pragma unroll
  for (int n = 0; n < 2; ++n) bn[n] = *(const short8*)(vrow0 + n * 16384);

#pragma unroll 2
  for (int ks = 0; ks < 32; ++ks) {
    short8 bc[2] = {bn[0], bn[1]};
    if (ks < 31) {
#pragma unroll
      for (int n = 0; n < 2; ++n)
        bn[n] = *(const short8*)(vrow0 + n * 16384 + (ks + 1) * 32);
    }
    short8 a[2];
#pragma unroll
    for (int m = 0; m < 2; ++m) {
      const int g = (m << 5) + ks;
      a[m] = *(const short8*)((const char*)p_lds + g * 1024 + ((lane ^ (g & 7)) << 4));
    }
#pragma unroll
    for (int m = 0; m < 2; ++m)
#pragma unroll
      for (int n = 0; n < 2; ++n)
        acc[m][n] = __builtin_amdgcn_mfma_f32_16x16x32_bf16(a[m], bc[n], acc[m][n], 0, 0, 0);
  }
#pragma unroll
  for (int m = 0; m < 2; ++m)
#pragma unroll
    for (int n = 0; n < 2; ++n)
#pragma unroll
      for (int r = 0; r < 4; ++r) {
        int gi = i0 + m * 16 + sb * 4 + r;
        if (gi < L)
          out_g[((size_t)b * L + gi) * H + w * 32 + n * 16 + ln16] = acc[m][n][r];
      }
}

// ----------------------------------------------------------------------------
extern "C" void kernel_launch(void* const* d_in, const int* in_sizes, int n_in,
                              void* d_out, int out_size, void* d_ws, size_t ws_size,
                              hipStream_t stream) {
  const float* q   = (const float*)d_in[0];
  const float* k   = (const float*)d_in[1];
  const float* v   = (const float*)d_in[2];
  const float* emb = (const float*)d_in[3];
  float* out  = (float*)d_out;
  float* attn = out + (size_t)B_DIM * L * H;

  // ws: vt 16MB | qe 1MB | qb 16MB | kb 16MB | lg 64MB  (113MB total; proven >=152MB avail)
  char* wsp = (char*)d_ws;
  ushort_t* vt = (ushort_t*)wsp;
  float*    qe = (float*)(wsp + (16u << 20));
  ushort_t* qb = (ushort_t*)(wsp + (17u << 20));
  ushort_t* kb = (ushort_t*)(wsp + (33u << 20));
  _Float16* lg = (_Float16*)(wsp + (49u << 20));

  qe_kernel<<<dim3((B_DIM * L) / 4), dim3(256), 0, stream>>>(q, emb, qe);
  vt_kernel<<<dim3(16, 4, B_DIM), dim3(256), 0, stream>>>(v, vt);
  convert_kernel<<<dim3(8192), dim3(256), 0, stream>>>(q, k, qb, kb);
  k1_gemm<<<dim3(2048), dim3(256), 0, stream>>>(qb, kb, qe, lg);
  k2_softmax_pv<<<dim3(1024), dim3(512), 0, stream>>>(vt, lg, attn, out);
}